// Round 7
// baseline (306.186 us; speedup 1.0000x reference)
//
#include <hip/hip_runtime.h>
#include <hip/hip_bf16.h>

#define Bn 1024
#define Lr 320
#define Dd 128
#define Ee 8
#define Pp 96

typedef short bf16x8 __attribute__((ext_vector_type(8)));
typedef float f32x4 __attribute__((ext_vector_type(4)));
typedef unsigned u32x4 __attribute__((ext_vector_type(4)));
typedef unsigned short u16;

__device__ __forceinline__ float cdf_f(float v) {
    return 0.5f * (1.0f + erff(v * 0.70710678118654752f));
}
__device__ __forceinline__ float softplus_f(float x) {
    return fmaxf(x, 0.0f) + log1pf(expf(-fabsf(x)));
}
__device__ __forceinline__ u16 f2bf(float f) {
    unsigned int u = __float_as_uint(f);
    return (u16)((u + 0x7fffu + ((u >> 16) & 1u)) >> 16);
}
__device__ __forceinline__ float bf2f(u16 u) {
    return __uint_as_float(((unsigned int)u) << 16);
}

// async global->LDS, 16 B per lane; LDS dest is wave-uniform base + lane*16.
__device__ __forceinline__ void gload16(const void* g, void* l) {
    __builtin_amdgcn_global_load_lds(
        (const __attribute__((address_space(1))) void*)g,
        (__attribute__((address_space(3))) void*)l, 16, 0, 0);
}

// expert_w fp32 [e][l][p] -> W_t bf16 [e][p][l] (l contiguous). 0.5 MB, L2-resident.
// Also zeroes accum (block 0) and zbuf (all 80 blocks), replacing memsets.
__global__ __launch_bounds__(256) void transpose_w(
    const float* __restrict__ ew, u16* __restrict__ wt,
    float* __restrict__ accum, float* __restrict__ zbuf)
{
    __shared__ float tile[Pp * 33];
    const int e  = blockIdx.x;       // 0..7
    const int l0 = blockIdx.y * 32;  // 0..288
    const int t  = threadIdx.x;
    if (e == 0 && blockIdx.y == 0 && t < 16) accum[t] = 0.f;
    {
        const int idx = (blockIdx.x * 10 + blockIdx.y) * 256 + t;  // 0..20479
        if (idx < Bn * 16) zbuf[idx] = 0.f;
    }
    #pragma unroll
    for (int i = 0; i < 12; ++i) {
        const int idx = t + 256 * i;            // 0..3071
        const int lp = idx / 96, p = idx - 96 * lp;
        tile[p * 33 + lp] = ew[((size_t)e * Lr + l0 + lp) * Pp + p];
    }
    __syncthreads();
    #pragma unroll
    for (int i = 0; i < 6; ++i) {
        const int g = t + 256 * i;              // 0..1535
        const int p = g >> 4, l2 = (g & 15) * 2;
        const unsigned pk = (unsigned)f2bf(tile[p * 33 + l2]) |
                            ((unsigned)f2bf(tile[p * 33 + l2 + 1]) << 16);
        *(unsigned*)&wt[((size_t)(e * Pp + p)) * Lr + l0 + l2] = pk;
    }
}

// K1 v2: streams x once (same access pattern / per-row dot order as the
// R3-verified g_kernel) and folds the gate projection in: after the 8-lane
// butterfly every lane holds g[b,l]; lane f8 accumulates g*w_gate[l,f8] and
// g*w_noise[l,f8] (coalesced, L1-hot), wave-tree + LDS + one device atomic
// per block into zbuf[b][0..7]=clean, [8..15]=noise-pre. Removes the
// latency-bound gate_kernel dot and the gbuf HBM round-trip.
__global__ __launch_bounds__(256, 8) void g2_kernel(
    const float* __restrict__ x, const float* __restrict__ start_w,
    const float* __restrict__ start_b, const float* __restrict__ w_gate,
    const float* __restrict__ w_noise, float* __restrict__ zbuf)
{
    __shared__ float sred[16];
    const int t  = threadIdx.x;
    const int lc = blockIdx.x;       // 0..4
    const int b  = blockIdx.y;       // 0..1023
    const float sb = start_b[0];
    const int f8 = t & 7;

    if (t < 16) sred[t] = 0.f;
    __syncthreads();

    float4 sw[4];
    #pragma unroll
    for (int j = 0; j < 4; ++j) sw[j] = ((const float4*)start_w)[f8 + 8 * j];

    const float* xb = x + ((size_t)b * Lr + lc * 64) * Dd;
    float zc = 0.f, zn = 0.f;
    #pragma unroll
    for (int p2 = 0; p2 < 2; ++p2) {
        const int r = p2 * 32 + (t >> 3);
        float acc = 0.f;
        #pragma unroll
        for (int j = 0; j < 4; ++j) {
            const float4 v = ((const float4*)(xb + (size_t)r * Dd))[f8 + 8 * j];
            acc += v.x * sw[j].x + v.y * sw[j].y + v.z * sw[j].z + v.w * sw[j].w;
        }
        #pragma unroll
        for (int off = 1; off <= 4; off <<= 1) acc += __shfl_xor(acc, off);
        const float gv = acc + sb;               // g[b, l] on all 8 lanes
        const int l = lc * 64 + r;
        zc += gv * w_gate[l * Ee + f8];
        zn += gv * w_noise[l * Ee + f8];
    }
    #pragma unroll
    for (int off = 8; off <= 32; off <<= 1) {
        zc += __shfl_xor(zc, off);
        zn += __shfl_xor(zn, off);
    }
    if ((t & 63) < 8) {
        atomicAdd(&sred[f8], zc);
        atomicAdd(&sred[8 + f8], zn);
    }
    __syncthreads();
    if (t < 16) atomicAdd(&zbuf[b * 16 + t], sred[t]);
}

// K1b v2: one THREAD per b (all-register O(8) work): softplus, noisy top-3,
// gates, prob; wave+block reduction of load/importance; 64 device atomics
// total. 4 blocks of 256.
__global__ __launch_bounds__(256) void topk_kernel(
    const float* __restrict__ zbuf, const float* __restrict__ noise,
    float* __restrict__ accum, float* __restrict__ gates_out)
{
    __shared__ float sred[16];
    const int t = threadIdx.x;
    const int b = blockIdx.x * 256 + t;

    if (t < 16) sred[t] = 0.f;
    __syncthreads();

    float zc[8], zn[8], nsy[8], sdv[8];
    #pragma unroll
    for (int e = 0; e < 8; ++e) {
        zc[e] = zbuf[b * 16 + e];
        zn[e] = zbuf[b * 16 + 8 + e];
    }
    #pragma unroll
    for (int e = 0; e < 8; ++e) {
        sdv[e] = softplus_f(zn[e]) + 0.01f;      // NOISE_EPS
        nsy[e] = zc[e] + noise[b * Ee + e] * sdv[e];
    }

    int i0 = -1, i1 = -1;
    float v0 = -INFINITY, v1 = -INFINITY, v2 = -INFINITY;
    #pragma unroll
    for (int i = 0; i < 8; ++i) if (nsy[i] > v0) { v0 = nsy[i]; i0 = i; }
    #pragma unroll
    for (int i = 0; i < 8; ++i) if (i != i0 && nsy[i] > v1) { v1 = nsy[i]; i1 = i; }
    #pragma unroll
    for (int i = 0; i < 8; ++i) if (i != i0 && i != i1 && nsy[i] > v2) { v2 = nsy[i]; }

    const float ex1 = expf(v1 - v0);
    const float den = 1.f + ex1;
    const float g0 = 1.f / den, g1 = ex1 / den;

    float im[8], pr[8];
    #pragma unroll
    for (int e = 0; e < 8; ++e) {
        im[e] = (e == i0) ? g0 : ((e == i1) ? g1 : 0.f);
        float c = zc[e];
        if (isnan(c)) c = 0.f;
        pr[e] = (nsy[e] > v2) ? cdf_f((c - v2) / sdv[e])
                              : cdf_f((c - v1) / sdv[e]);
        gates_out[b * Ee + e] = im[e];
    }

    #pragma unroll
    for (int off = 1; off <= 32; off <<= 1) {
        #pragma unroll
        for (int e = 0; e < 8; ++e) {
            pr[e] += __shfl_xor(pr[e], off);
            im[e] += __shfl_xor(im[e], off);
        }
    }
    if ((t & 63) == 0) {
        #pragma unroll
        for (int e = 0; e < 8; ++e) {
            atomicAdd(&sred[e], pr[e]);          // load
            atomicAdd(&sred[8 + e], im[e]);      // importance
        }
    }
    __syncthreads();
    if (t < 16) atomicAdd(&accum[t], sred[t]);
}

// K2 v4 (R6-verified, unchanged): W dbuf in LDS (R3 staging/swizzle verbatim,
// 24 KB); x fragments direct from global (L2/L3-warm) into ping-pong register
// arrays with a manual 1-tile software pipeline. Block 0 also computes the
// loss (accum final after topk). grid 2048 = (b, d-half).
__global__ __launch_bounds__(256, 4) void mm_kernel(
    const float* __restrict__ x, const u16* __restrict__ wt,
    const float* __restrict__ expert_b, const float* __restrict__ gates,
    const float* __restrict__ accum, float* __restrict__ out)
{
    __shared__ __align__(16) unsigned Ws[2][192 * 16];   // 24 KB

    const int tid  = threadIdx.x;

    // folded loss (runs while other blocks stage; accum final before launch)
    if (blockIdx.x == 0 && tid == 0) {
        float lo[8], im[8];
        #pragma unroll
        for (int i = 0; i < 8; ++i) { lo[i] = accum[i]; im[i] = accum[8 + i]; }
        float ml = 0.f, mi = 0.f;
        #pragma unroll
        for (int i = 0; i < 8; ++i) { ml += lo[i]; mi += im[i]; }
        ml *= 0.125f; mi *= 0.125f;
        float sl = 0.f, si = 0.f;
        #pragma unroll
        for (int i = 0; i < 8; ++i) {
            const float dl = lo[i] - ml, di = im[i] - mi;
            sl += dl * dl; si += di * di;
        }
        const float cvl = (sl / 7.f) / (ml * ml + 1e-10f);
        const float cvi = (si / 7.f) / (mi * mi + 1e-10f);
        float* os = out + (size_t)Bn * Pp * Dd;
        os[0] = 0.01f * (cvi + cvl);
        os[1] = 0.0f;
    }

    const int b    = blockIdx.x >> 1;
    const int h    = blockIdx.x & 1;              // d-half
    const int lane = tid & 63;
    const int wv   = tid >> 6;                    // wave = n-tile (16 d)
    const int quad = lane >> 4;
    const int r16  = lane & 15;

    // top-2 experts (gates has exactly 2 nonzeros per b)
    int e0 = 0, e1 = 0; float g0 = 0.f, g1 = 0.f; int cnt = 0;
    #pragma unroll
    for (int e = 0; e < Ee; ++e) {
        const float gv = gates[b * Ee + e];
        if (gv != 0.f) {
            if (cnt == 0) { e0 = e; g0 = gv; }
            else if (cnt == 1) { e1 = e; g1 = gv; }
            ++cnt;
        }
    }

    const u16* w0r = wt + (size_t)e0 * Pp * Lr;
    const u16* w1r = wt + (size_t)e1 * Pp * Lr;

    const int d = h * 64 + 16 * wv + r16;          // output column of this lane
    const float* xg = x + ((size_t)b * Lr + 8 * quad) * Dd + d;

    // W staging lane constants (round-3 scheme verbatim)
    const int wrow = lane >> 2;      // row within 16-row W chunk
    const int wq   = lane & 3;       // 16B-quad within W row

    auto STAGE_W = [&](int buf, int l0) {
        #pragma unroll
        for (int i = 0; i < 3; ++i) {
            const int c  = 3 * wv + i;                         // 0..11
            const int r  = 16 * c + wrow;                      // 0..191
            const int dw = (4 * wq) ^ ((r & 3) << 2);          // swizzled src dword
            const u16* src = (c < 6) ? (w0r + (size_t)r * Lr)
                                     : (w1r + (size_t)(r - 96) * Lr);
            gload16(src + l0 + 2 * dw, (void*)&Ws[buf][c * 256]);
        }
    };

    float xa[8], xb8[8];
    auto LOADX = [&](float* dst, int l0) {
        #pragma unroll
        for (int k = 0; k < 8; ++k)
            dst[k] = xg[(size_t)(l0 + k) * Dd];
    };

    f32x4 a0[6], a1[6];
    #pragma unroll
    for (int m = 0; m < 6; ++m) {
        a0[m] = (f32x4){0.f, 0.f, 0.f, 0.f};
        a1[m] = (f32x4){0.f, 0.f, 0.f, 0.f};
    }

    const int wdw = (4 * quad) ^ ((r16 & 3) << 2);  // Ws read swizzle (R3)

    union UF { u32x4 q; bf16x8 v; unsigned u[4]; };

    auto COMPUTE = [&](int buf, const float* xv) {
        UF xf;
        #pragma unroll
        for (int k2 = 0; k2 < 4; ++k2)
            xf.u[k2] = (unsigned)f2bf(xv[2 * k2]) |
                       ((unsigned)f2bf(xv[2 * k2 + 1]) << 16);
        #pragma unroll
        for (int m = 0; m < 6; ++m) {
            UF f0, f1;
            f0.q = *(const u32x4*)&Ws[buf][(16 * m + r16) * 16 + wdw];
            f1.q = *(const u32x4*)&Ws[buf][(96 + 16 * m + r16) * 16 + wdw];
            a0[m] = __builtin_amdgcn_mfma_f32_16x16x32_bf16(f0.v, xf.v, a0[m], 0, 0, 0);
            a1[m] = __builtin_amdgcn_mfma_f32_16x16x32_bf16(f1.v, xf.v, a1[m], 0, 0, 0);
        }
    };

    STAGE_W(0, 0);
    LOADX(xa, 0);
    __syncthreads();

    #pragma unroll
    for (int t = 0; t < 10; t += 2) {
        // phase A: tile t (even) in Ws[0] / xa; prefetch tile t+1
        STAGE_W(1, 32 * (t + 1));
        LOADX(xb8, 32 * (t + 1));
        COMPUTE(0, xa);
        __syncthreads();
        // phase B: tile t+1 (odd) in Ws[1] / xb8; prefetch tile t+2
        if (t + 2 < 10) {
            STAGE_W(0, 32 * (t + 2));
            LOADX(xa, 32 * (t + 2));
        }
        COMPUTE(1, xb8);
        __syncthreads();
    }

    // epilogue: fp32 combine + bias. C/D layout: col(d)=r16, row(p)=4*quad+reg
    const float* eb0 = expert_b + (size_t)e0 * Pp * Dd;
    const float* eb1 = expert_b + (size_t)e1 * Pp * Dd;
    #pragma unroll
    for (int m = 0; m < 6; ++m) {
        #pragma unroll
        for (int r = 0; r < 4; ++r) {
            const int p = 16 * m + 4 * quad + r;
            out[((size_t)b * Pp + p) * Dd + d] =
                g0 * (a0[m][r] + eb0[p * Dd + d]) +
                g1 * (a1[m][r] + eb1[p * Dd + d]);
        }
    }
}

extern "C" void kernel_launch(void* const* d_in, const int* in_sizes, int n_in,
                              void* d_out, int out_size, void* d_ws, size_t ws_size,
                              hipStream_t stream)
{
    const float* x        = (const float*)d_in[0];
    // d_in[1] = x_mark_enc (unused)
    const float* noise    = (const float*)d_in[2];
    const float* start_w  = (const float*)d_in[3];
    const float* start_b  = (const float*)d_in[4];
    const float* w_gate   = (const float*)d_in[5];
    const float* w_noise  = (const float*)d_in[6];
    const float* expert_w = (const float*)d_in[7];
    const float* expert_b = (const float*)d_in[8];
    float* out            = (float*)d_out;

    float* accum = (float*)d_ws;                 // 16 f
    float* gates = accum + 16;                   // 8192 f
    float* zbuf  = gates + Bn * Ee;              // 16384 f
    u16*   wt    = (u16*)(zbuf + Bn * 16);       // 8*96*320 bf16

    hipLaunchKernelGGL(transpose_w, dim3(Ee, Lr / 32), dim3(256), 0, stream,
                       expert_w, wt, accum, zbuf);
    hipLaunchKernelGGL(g2_kernel, dim3(5, Bn), dim3(256), 0, stream,
                       x, start_w, start_b, w_gate, w_noise, zbuf);
    hipLaunchKernelGGL(topk_kernel, dim3(Bn / 256), dim3(256), 0, stream,
                       zbuf, noise, accum, gates);
    hipLaunchKernelGGL(mm_kernel, dim3(Bn * 2), dim3(256), 0, stream,
                       x, wt, expert_b, gates, accum, out);
}

// Round 8
// 300.639 us; speedup vs baseline: 1.0185x; 1.0185x over previous
//
#include <hip/hip_runtime.h>
#include <hip/hip_bf16.h>

#define Bn 1024
#define Lr 320
#define Dd 128
#define Ee 8
#define Pp 96

typedef short bf16x8 __attribute__((ext_vector_type(8)));
typedef float f32x4 __attribute__((ext_vector_type(4)));
typedef unsigned u32x4 __attribute__((ext_vector_type(4)));
typedef unsigned short u16;

__device__ __forceinline__ float cdf_f(float v) {
    return 0.5f * (1.0f + erff(v * 0.70710678118654752f));
}
__device__ __forceinline__ float softplus_f(float x) {
    return fmaxf(x, 0.0f) + log1pf(expf(-fabsf(x)));
}
__device__ __forceinline__ u16 f2bf(float f) {
    unsigned int u = __float_as_uint(f);
    return (u16)((u + 0x7fffu + ((u >> 16) & 1u)) >> 16);
}
__device__ __forceinline__ float bf2f(u16 u) {
    return __uint_as_float(((unsigned int)u) << 16);
}

// async global->LDS, 16 B per lane; LDS dest is wave-uniform base + lane*16.
__device__ __forceinline__ void gload16(const void* g, void* l) {
    __builtin_amdgcn_global_load_lds(
        (const __attribute__((address_space(1))) void*)g,
        (__attribute__((address_space(3))) void*)l, 16, 0, 0);
}

// K1 (R7-verified structure): streams x once, folds the gate projection in.
// After the 8-lane butterfly every lane holds g[b,l]; lane f8 accumulates
// g*w_gate[l,f8] / g*w_noise[l,f8]; wave-tree + LDS reduce, then each block
// writes ITS OWN zbuf slot [b][lc][16] (no device atomics, no zero-init).
__global__ __launch_bounds__(256, 8) void g2_kernel(
    const float* __restrict__ x, const float* __restrict__ start_w,
    const float* __restrict__ start_b, const float* __restrict__ w_gate,
    const float* __restrict__ w_noise, float* __restrict__ zbuf)
{
    __shared__ float sred[16];
    const int t  = threadIdx.x;
    const int lc = blockIdx.x;       // 0..4
    const int b  = blockIdx.y;       // 0..1023
    const float sb = start_b[0];
    const int f8 = t & 7;

    if (t < 16) sred[t] = 0.f;
    __syncthreads();

    float4 sw[4];
    #pragma unroll
    for (int j = 0; j < 4; ++j) sw[j] = ((const float4*)start_w)[f8 + 8 * j];

    const float* xb = x + ((size_t)b * Lr + lc * 64) * Dd;
    float zc = 0.f, zn = 0.f;
    #pragma unroll
    for (int p2 = 0; p2 < 2; ++p2) {
        const int r = p2 * 32 + (t >> 3);
        float acc = 0.f;
        #pragma unroll
        for (int j = 0; j < 4; ++j) {
            const float4 v = ((const float4*)(xb + (size_t)r * Dd))[f8 + 8 * j];
            acc += v.x * sw[j].x + v.y * sw[j].y + v.z * sw[j].z + v.w * sw[j].w;
        }
        #pragma unroll
        for (int off = 1; off <= 4; off <<= 1) acc += __shfl_xor(acc, off);
        const float gv = acc + sb;               // g[b, l] on all 8 lanes
        const int l = lc * 64 + r;
        zc += gv * w_gate[l * Ee + f8];
        zn += gv * w_noise[l * Ee + f8];
    }
    #pragma unroll
    for (int off = 8; off <= 32; off <<= 1) {
        zc += __shfl_xor(zc, off);
        zn += __shfl_xor(zn, off);
    }
    if ((t & 63) < 8) {
        atomicAdd(&sred[f8], zc);        // LDS (intra-block) atomics only
        atomicAdd(&sred[8 + f8], zn);
    }
    __syncthreads();
    if (t < 16) zbuf[(b * 5 + lc) * 16 + t] = sred[t];
}

// Fused topk + transpose_w (independent work, one dispatch, 84 blocks):
// blocks 0..3  : one THREAD per b — sum zbuf partials, softplus, noisy top-3,
//                gates, prob; block-reduced load/importance written to
//                lossbuf[blk][16] (no device atomics, no zero-init).
// blocks 4..83 : expert_w fp32 [e][l][p] -> wt bf16 [e][p][l] (verbatim R3).
__global__ __launch_bounds__(256) void tk_tr_kernel(
    const float* __restrict__ zbuf, const float* __restrict__ noise,
    const float* __restrict__ ew, u16* __restrict__ wt,
    float* __restrict__ lossbuf, float* __restrict__ gates_out)
{
    __shared__ float tile[Pp * 33];
    const int t = threadIdx.x;

    if (blockIdx.x >= 4) {            // ---- transpose path ----
        const int bx = blockIdx.x - 4;           // 0..79
        const int e  = bx / 10;                  // 0..7
        const int l0 = (bx - 10 * e) * 32;       // 0..288
        #pragma unroll
        for (int i = 0; i < 12; ++i) {
            const int idx = t + 256 * i;         // 0..3071
            const int lp = idx / 96, p = idx - 96 * lp;
            tile[p * 33 + lp] = ew[((size_t)e * Lr + l0 + lp) * Pp + p];
        }
        __syncthreads();
        #pragma unroll
        for (int i = 0; i < 6; ++i) {
            const int g = t + 256 * i;           // 0..1535
            const int p = g >> 4, l2 = (g & 15) * 2;
            const unsigned pk = (unsigned)f2bf(tile[p * 33 + l2]) |
                                ((unsigned)f2bf(tile[p * 33 + l2 + 1]) << 16);
            *(unsigned*)&wt[((size_t)(e * Pp + p)) * Lr + l0 + l2] = pk;
        }
        return;
    }

    // ---- topk path (blocks 0..3) ----
    float* sred = tile;               // reuse LDS
    const int b = blockIdx.x * 256 + t;

    if (t < 16) sred[t] = 0.f;
    __syncthreads();

    float zc[8], zn[8], nsy[8], sdv[8];
    #pragma unroll
    for (int e = 0; e < 8; ++e) { zc[e] = 0.f; zn[e] = 0.f; }
    #pragma unroll
    for (int lc = 0; lc < 5; ++lc) {
        #pragma unroll
        for (int e = 0; e < 8; ++e) {
            zc[e] += zbuf[(b * 5 + lc) * 16 + e];
            zn[e] += zbuf[(b * 5 + lc) * 16 + 8 + e];
        }
    }
    #pragma unroll
    for (int e = 0; e < 8; ++e) {
        sdv[e] = softplus_f(zn[e]) + 0.01f;      // NOISE_EPS
        nsy[e] = zc[e] + noise[b * Ee + e] * sdv[e];
    }

    int i0 = -1, i1 = -1;
    float v0 = -INFINITY, v1 = -INFINITY, v2 = -INFINITY;
    #pragma unroll
    for (int i = 0; i < 8; ++i) if (nsy[i] > v0) { v0 = nsy[i]; i0 = i; }
    #pragma unroll
    for (int i = 0; i < 8; ++i) if (i != i0 && nsy[i] > v1) { v1 = nsy[i]; i1 = i; }
    #pragma unroll
    for (int i = 0; i < 8; ++i) if (i != i0 && i != i1 && nsy[i] > v2) { v2 = nsy[i]; }

    const float ex1 = expf(v1 - v0);
    const float den = 1.f + ex1;
    const float g0 = 1.f / den, g1 = ex1 / den;

    float im[8], pr[8];
    #pragma unroll
    for (int e = 0; e < 8; ++e) {
        im[e] = (e == i0) ? g0 : ((e == i1) ? g1 : 0.f);
        float c = zc[e];
        if (isnan(c)) c = 0.f;
        pr[e] = (nsy[e] > v2) ? cdf_f((c - v2) / sdv[e])
                              : cdf_f((c - v1) / sdv[e]);
        gates_out[b * Ee + e] = im[e];
    }

    #pragma unroll
    for (int off = 1; off <= 32; off <<= 1) {
        #pragma unroll
        for (int e = 0; e < 8; ++e) {
            pr[e] += __shfl_xor(pr[e], off);
            im[e] += __shfl_xor(im[e], off);
        }
    }
    if ((t & 63) == 0) {
        #pragma unroll
        for (int e = 0; e < 8; ++e) {
            atomicAdd(&sred[e], pr[e]);          // LDS atomics (intra-block)
            atomicAdd(&sred[8 + e], im[e]);
        }
    }
    __syncthreads();
    if (t < 16) lossbuf[blockIdx.x * 16 + t] = sred[t];
}

// K2 v5: h-merged (one block per b, 512 threads, 8 waves = 8 n-tiles over the
// full 128 d). W tiles staged ONCE per b (was twice): same R3 staging/swizzle,
// 12 chunks split across 8 waves. x fragments direct from global (L2/L3-warm)
// into ping-pong registers, 1-tile software pipeline (R6-verified). Block 0
// sums lossbuf partials -> loss. LDS 24 KB, launch_bounds(512,2) = 16 waves/CU.
__global__ __launch_bounds__(512, 2) void mm_kernel(
    const float* __restrict__ x, const u16* __restrict__ wt,
    const float* __restrict__ expert_b, const float* __restrict__ gates,
    const float* __restrict__ lossbuf, float* __restrict__ out)
{
    __shared__ __align__(16) unsigned Ws[2][192 * 16];   // 24 KB

    const int tid = threadIdx.x;

    // folded loss (accum partials final: tk_tr completed before this launch)
    if (blockIdx.x == 0 && tid == 0) {
        float lo[8], im[8];
        #pragma unroll
        for (int i = 0; i < 8; ++i) {
            lo[i] = lossbuf[i]      + lossbuf[16 + i] +
                    lossbuf[32 + i] + lossbuf[48 + i];
            im[i] = lossbuf[8 + i]  + lossbuf[24 + i] +
                    lossbuf[40 + i] + lossbuf[56 + i];
        }
        float ml = 0.f, mi = 0.f;
        #pragma unroll
        for (int i = 0; i < 8; ++i) { ml += lo[i]; mi += im[i]; }
        ml *= 0.125f; mi *= 0.125f;
        float sl = 0.f, si = 0.f;
        #pragma unroll
        for (int i = 0; i < 8; ++i) {
            const float dl = lo[i] - ml, di = im[i] - mi;
            sl += dl * dl; si += di * di;
        }
        const float cvl = (sl / 7.f) / (ml * ml + 1e-10f);
        const float cvi = (si / 7.f) / (mi * mi + 1e-10f);
        float* os = out + (size_t)Bn * Pp * Dd;
        os[0] = 0.01f * (cvi + cvl);
        os[1] = 0.0f;
    }

    const int b    = blockIdx.x;
    const int lane = tid & 63;
    const int wv   = tid >> 6;                    // 0..7
    const int hh   = wv >> 2;                     // d-half
    const int nt   = wv & 3;                      // n-tile within half
    const int quad = lane >> 4;
    const int r16  = lane & 15;

    // top-2 experts (gates has exactly 2 nonzeros per b)
    int e0 = 0, e1 = 0; float g0 = 0.f, g1 = 0.f; int cnt = 0;
    #pragma unroll
    for (int e = 0; e < Ee; ++e) {
        const float gv = gates[b * Ee + e];
        if (gv != 0.f) {
            if (cnt == 0) { e0 = e; g0 = gv; }
            else if (cnt == 1) { e1 = e; g1 = gv; }
            ++cnt;
        }
    }

    const u16* w0r = wt + (size_t)e0 * Pp * Lr;
    const u16* w1r = wt + (size_t)e1 * Pp * Lr;

    const int d = hh * 64 + nt * 16 + r16;         // output column of this lane
    const float* xg = x + ((size_t)b * Lr + 8 * quad) * Dd + d;

    // W staging lane constants (R3 scheme; 12 chunks over 8 waves: wv, and
    // 8+wv for wv<4)
    const int wrow = lane >> 2;      // row within 16-row W chunk
    const int wq   = lane & 3;       // 16B-quad within W row

    auto STAGE_W = [&](int buf, int l0) {
        {
            const int c  = wv;                                 // 0..7
            const int r  = 16 * c + wrow;
            const int dw = (4 * wq) ^ ((r & 3) << 2);
            const u16* src = (c < 6) ? (w0r + (size_t)r * Lr)
                                     : (w1r + (size_t)(r - 96) * Lr);
            gload16(src + l0 + 2 * dw, (void*)&Ws[buf][c * 256]);
        }
        if (wv < 4) {
            const int c  = 8 + wv;                             // 8..11
            const int r  = 16 * c + wrow;
            const int dw = (4 * wq) ^ ((r & 3) << 2);
            const u16* src = w1r + (size_t)(r - 96) * Lr;      // c >= 6 always
            gload16(src + l0 + 2 * dw, (void*)&Ws[buf][c * 256]);
        }
    };

    float xa[8], xb8[8];
    auto LOADX = [&](float* dst, int l0) {
        #pragma unroll
        for (int k = 0; k < 8; ++k)
            dst[k] = xg[(size_t)(l0 + k) * Dd];
    };

    f32x4 a0[6], a1[6];
    #pragma unroll
    for (int m = 0; m < 6; ++m) {
        a0[m] = (f32x4){0.f, 0.f, 0.f, 0.f};
        a1[m] = (f32x4){0.f, 0.f, 0.f, 0.f};
    }

    const int wdw = (4 * quad) ^ ((r16 & 3) << 2);  // Ws read swizzle (R3)

    union UF { u32x4 q; bf16x8 v; unsigned u[4]; };

    auto COMPUTE = [&](int buf, const float* xv) {
        UF xf;
        #pragma unroll
        for (int k2 = 0; k2 < 4; ++k2)
            xf.u[k2] = (unsigned)f2bf(xv[2 * k2]) |
                       ((unsigned)f2bf(xv[2 * k2 + 1]) << 16);
        #pragma unroll
        for (int m = 0; m < 6; ++m) {
            UF f0, f1;
            f0.q = *(const u32x4*)&Ws[buf][(16 * m + r16) * 16 + wdw];
            f1.q = *(const u32x4*)&Ws[buf][(96 + 16 * m + r16) * 16 + wdw];
            a0[m] = __builtin_amdgcn_mfma_f32_16x16x32_bf16(f0.v, xf.v, a0[m], 0, 0, 0);
            a1[m] = __builtin_amdgcn_mfma_f32_16x16x32_bf16(f1.v, xf.v, a1[m], 0, 0, 0);
        }
    };

    STAGE_W(0, 0);
    LOADX(xa, 0);
    __syncthreads();

    #pragma unroll
    for (int t = 0; t < 10; t += 2) {
        // phase A: tile t (even) in Ws[0] / xa; prefetch tile t+1
        STAGE_W(1, 32 * (t + 1));
        LOADX(xb8, 32 * (t + 1));
        COMPUTE(0, xa);
        __syncthreads();
        // phase B: tile t+1 (odd) in Ws[1] / xb8; prefetch tile t+2
        if (t + 2 < 10) {
            STAGE_W(0, 32 * (t + 2));
            LOADX(xa, 32 * (t + 2));
        }
        COMPUTE(1, xb8);
        __syncthreads();
    }

    // epilogue: fp32 combine + bias. C/D layout: col(d)=r16, row(p)=4*quad+reg
    const float* eb0 = expert_b + (size_t)e0 * Pp * Dd;
    const float* eb1 = expert_b + (size_t)e1 * Pp * Dd;
    #pragma unroll
    for (int m = 0; m < 6; ++m) {
        #pragma unroll
        for (int r = 0; r < 4; ++r) {
            const int p = 16 * m + 4 * quad + r;
            out[((size_t)b * Pp + p) * Dd + d] =
                g0 * (a0[m][r] + eb0[p * Dd + d]) +
                g1 * (a1[m][r] + eb1[p * Dd + d]);
        }
    }
}

extern "C" void kernel_launch(void* const* d_in, const int* in_sizes, int n_in,
                              void* d_out, int out_size, void* d_ws, size_t ws_size,
                              hipStream_t stream)
{
    const float* x        = (const float*)d_in[0];
    // d_in[1] = x_mark_enc (unused)
    const float* noise    = (const float*)d_in[2];
    const float* start_w  = (const float*)d_in[3];
    const float* start_b  = (const float*)d_in[4];
    const float* w_gate   = (const float*)d_in[5];
    const float* w_noise  = (const float*)d_in[6];
    const float* expert_w = (const float*)d_in[7];
    const float* expert_b = (const float*)d_in[8];
    float* out            = (float*)d_out;

    float* gates   = (float*)d_ws;               // 8192 f
    float* zbuf    = gates + Bn * Ee;            // 1024*5*16 f
    float* lossbuf = zbuf + Bn * 80;             // 64 f
    u16*   wt      = (u16*)(lossbuf + 64);       // 8*96*320 bf16

    hipLaunchKernelGGL(g2_kernel, dim3(5, Bn), dim3(256), 0, stream,
                       x, start_w, start_b, w_gate, w_noise, zbuf);
    hipLaunchKernelGGL(tk_tr_kernel, dim3(84), dim3(256), 0, stream,
                       zbuf, noise, expert_w, wt, lossbuf, gates);
    hipLaunchKernelGGL(mm_kernel, dim3(Bn), dim3(512), 0, stream,
                       x, wt, expert_b, gates, lossbuf, out);
}